// Round 4
// baseline (80.328 us; speedup 1.0000x reference)
//
#include <hip/hip_runtime.h>

// transforms_blue: u=floor(x*255); gray=round(.114*u0+.587*u1+.299*u2);
// where gray<128: c0=min(gray+60,255), c1=min(gray+10,255); c2=gray; out=c/255.
// Golden theory: numpy recompute of the reference on the f32 inputs with
// numpy dtype semantics -> ALL f32, separately-rounded mul/add (NO fma),
// left-assoc sum, np.round = rint half-to-even, true f32 division by 255.
// NOTE: HIP's __fmul_rn/__fadd_rn are plain a*b/a+b inline wrappers and do
// NOT block contraction (they inline from header scope with contract=fast);
// the ops must be written lexically under `#pragma clang fp contract(off)`.
// Input [64,3,512,512] f32, output f32. Memory-bound elementwise.

static constexpr int HW   = 512 * 512;   // 262144 pixels per plane
static constexpr int HW4  = HW / 4;      // 65536 float4s per plane
static constexpr int NB   = 64;          // batch

__device__ __forceinline__ void px(float x0, float x1, float x2,
                                   float& o0, float& o1, float& o2) {
    #pragma clang fp contract(off)
    // u = floor(x*255) in f32 (numpy: f32_array * python_float -> f32)
    float p0 = x0 * 255.0f;
    float p1 = x1 * 255.0f;
    float p2 = x2 * 255.0f;
    float u0 = floorf(p0);
    float u1 = floorf(p1);
    float u2 = floorf(p2);
    // gray: separately rounded f32 muls and adds, left-to-right, NO fma.
    float t0 = 0.114f * u0;
    float t1 = 0.587f * u1;
    float t2 = 0.299f * u2;
    float s01 = t0 + t1;
    float sum = s01 + t2;
    float g = rintf(sum);            // np.round == rint, half-to-even
    float c0 = g, c1 = g;
    if (g < 128.0f) {
        float a0 = g + 60.0f;
        float a1 = g + 10.0f;
        c0 = fminf(a0, 255.0f);
        c1 = fminf(a1, 255.0f);
    }
    // numpy: out / 255.0 -> true IEEE f32 division (not reciprocal mul)
    o0 = c0 / 255.0f;
    o1 = c1 / 255.0f;
    o2 = g  / 255.0f;
}

__global__ void transforms_blue_kernel(const float* __restrict__ in,
                                       float* __restrict__ out,
                                       int total_vec) {
    const int stride = gridDim.x * blockDim.x;
    for (int v = blockIdx.x * blockDim.x + threadIdx.x; v < total_vec; v += stride) {
        int b   = v >> 16;           // v / HW4  (HW4 == 65536)
        int hw4 = v & (HW4 - 1);     // v % HW4
        size_t base = (size_t)b * 3 * HW + (size_t)hw4 * 4;

        float4 a0 = *reinterpret_cast<const float4*>(in + base);
        float4 a1 = *reinterpret_cast<const float4*>(in + base + HW);
        float4 a2 = *reinterpret_cast<const float4*>(in + base + 2 * HW);

        float4 o0, o1, o2;
        px(a0.x, a1.x, a2.x, o0.x, o1.x, o2.x);
        px(a0.y, a1.y, a2.y, o0.y, o1.y, o2.y);
        px(a0.z, a1.z, a2.z, o0.z, o1.z, o2.z);
        px(a0.w, a1.w, a2.w, o0.w, o1.w, o2.w);

        *reinterpret_cast<float4*>(out + base)          = o0;
        *reinterpret_cast<float4*>(out + base + HW)     = o1;
        *reinterpret_cast<float4*>(out + base + 2 * HW) = o2;
    }
}

extern "C" void kernel_launch(void* const* d_in, const int* in_sizes, int n_in,
                              void* d_out, int out_size, void* d_ws, size_t ws_size,
                              hipStream_t stream) {
    const float* in = (const float*)d_in[0];
    float* out = (float*)d_out;

    const int total_vec = NB * HW4;  // 4,194,304 quads
    const int block = 256;
    const int grid = 2048;           // grid-stride: ~8 iters/thread

    transforms_blue_kernel<<<grid, block, 0, stream>>>(in, out, total_vec);
}

// Round 7
// 70.837 us; speedup vs baseline: 1.1340x; 1.1340x over previous
//
#include <hip/hip_runtime.h>

// transforms_blue: u=floor(x*255); gray=round(.114*u0+.587*u1+.299*u2);
// where gray<128: c0=min(gray+60,255), c1=min(gray+10,255); c2=gray; out=c/255.
// Golden = all-f32 numpy-order pipeline (R4 passed with absmax 0.0):
// separately-rounded f32 mul/add (contract(off) IN SCOPE), left-assoc sum,
// rintf (half-to-even), true IEEE f32 division. DO NOT alter the numerics.
// R7: ext_vector elements aren't reference-bindable -> px returns by value.
// Nontemporal ld/st (streaming, touched once); grid 4096 for MLP.
// Input [64,3,512,512] f32, output f32. Memory-bound: 403 MB total traffic.

typedef float f32x4 __attribute__((ext_vector_type(4)));

static constexpr int HW   = 512 * 512;   // 262144 pixels per plane
static constexpr int HW4  = HW / 4;      // 65536 float4s per plane
static constexpr int NB   = 64;          // batch

struct Px { float o0, o1, o2; };

__device__ __forceinline__ Px px(float x0, float x1, float x2) {
    #pragma clang fp contract(off)
    float p0 = x0 * 255.0f;
    float p1 = x1 * 255.0f;
    float p2 = x2 * 255.0f;
    float u0 = floorf(p0);
    float u1 = floorf(p1);
    float u2 = floorf(p2);
    float t0 = 0.114f * u0;
    float t1 = 0.587f * u1;
    float t2 = 0.299f * u2;
    float s01 = t0 + t1;
    float sum = s01 + t2;
    float g = rintf(sum);            // np.round == rint, half-to-even
    float c0 = g, c1 = g;
    if (g < 128.0f) {
        float a0 = g + 60.0f;
        float a1 = g + 10.0f;
        c0 = fminf(a0, 255.0f);
        c1 = fminf(a1, 255.0f);
    }
    Px r;
    r.o0 = c0 / 255.0f;              // true IEEE f32 division (numpy)
    r.o1 = c1 / 255.0f;
    r.o2 = g  / 255.0f;
    return r;
}

__global__ void transforms_blue_kernel(const float* __restrict__ in,
                                       float* __restrict__ out,
                                       int total_vec) {
    const int stride = gridDim.x * blockDim.x;
    for (int v = blockIdx.x * blockDim.x + threadIdx.x; v < total_vec; v += stride) {
        int b   = v >> 16;           // v / HW4  (HW4 == 65536)
        int hw4 = v & (HW4 - 1);     // v % HW4
        size_t base = (size_t)b * 3 * HW + (size_t)hw4 * 4;

        f32x4 a0 = __builtin_nontemporal_load(reinterpret_cast<const f32x4*>(in + base));
        f32x4 a1 = __builtin_nontemporal_load(reinterpret_cast<const f32x4*>(in + base + HW));
        f32x4 a2 = __builtin_nontemporal_load(reinterpret_cast<const f32x4*>(in + base + 2 * HW));

        Px rx = px(a0.x, a1.x, a2.x);
        Px ry = px(a0.y, a1.y, a2.y);
        Px rz = px(a0.z, a1.z, a2.z);
        Px rw = px(a0.w, a1.w, a2.w);

        f32x4 o0 = { rx.o0, ry.o0, rz.o0, rw.o0 };
        f32x4 o1 = { rx.o1, ry.o1, rz.o1, rw.o1 };
        f32x4 o2 = { rx.o2, ry.o2, rz.o2, rw.o2 };

        __builtin_nontemporal_store(o0, reinterpret_cast<f32x4*>(out + base));
        __builtin_nontemporal_store(o1, reinterpret_cast<f32x4*>(out + base + HW));
        __builtin_nontemporal_store(o2, reinterpret_cast<f32x4*>(out + base + 2 * HW));
    }
}

extern "C" void kernel_launch(void* const* d_in, const int* in_sizes, int n_in,
                              void* d_out, int out_size, void* d_ws, size_t ws_size,
                              hipStream_t stream) {
    const float* in = (const float*)d_in[0];
    float* out = (float*)d_out;

    const int total_vec = NB * HW4;  // 4,194,304 quads
    const int block = 256;
    const int grid = 4096;           // grid-stride: ~4 iters/thread

    transforms_blue_kernel<<<grid, block, 0, stream>>>(in, out, total_vec);
}

// Round 8
// 67.647 us; speedup vs baseline: 1.1874x; 1.0471x over previous
//
#include <hip/hip_runtime.h>

// transforms_blue: u=floor(x*255); gray=round(.114*u0+.587*u1+.299*u2);
// where gray<128: c0=min(gray+60,255), c1=min(gray+10,255); c2=gray; out=c/255.
// Golden = all-f32 numpy-order pipeline (R4/R7 passed, absmax 0.0):
// separately-rounded f32 mul/add (contract(off) IN SCOPE), left-assoc sum,
// rintf (half-to-even), true IEEE f32 division. DO NOT alter the numerics.
// R8: fixed 2 quads/thread (grid 8192x256 covers 4,194,304 quads exactly);
// all 6 nt loads issued up front (2x MLP vs grid-stride loop), no loop branch.
// Input [64,3,512,512] f32, output f32. Memory-bound: 403 MB total traffic.

typedef float f32x4 __attribute__((ext_vector_type(4)));

static constexpr int HW   = 512 * 512;   // 262144 pixels per plane
static constexpr int HW4  = HW / 4;      // 65536 float4s per plane
static constexpr int NB   = 64;          // batch
static constexpr int NTHREADS = 8192 * 256;  // 2,097,152 = total_vec / 2

struct Px { float o0, o1, o2; };

__device__ __forceinline__ Px px(float x0, float x1, float x2) {
    #pragma clang fp contract(off)
    float p0 = x0 * 255.0f;
    float p1 = x1 * 255.0f;
    float p2 = x2 * 255.0f;
    float u0 = floorf(p0);
    float u1 = floorf(p1);
    float u2 = floorf(p2);
    float t0 = 0.114f * u0;
    float t1 = 0.587f * u1;
    float t2 = 0.299f * u2;
    float s01 = t0 + t1;
    float sum = s01 + t2;
    float g = rintf(sum);            // np.round == rint, half-to-even
    float c0 = g, c1 = g;
    if (g < 128.0f) {
        float a0 = g + 60.0f;
        float a1 = g + 10.0f;
        c0 = fminf(a0, 255.0f);
        c1 = fminf(a1, 255.0f);
    }
    Px r;
    r.o0 = c0 / 255.0f;              // true IEEE f32 division (numpy)
    r.o1 = c1 / 255.0f;
    r.o2 = g  / 255.0f;
    return r;
}

__device__ __forceinline__ size_t quad_base(int v) {
    int b   = v >> 16;               // v / HW4  (HW4 == 65536)
    int hw4 = v & (HW4 - 1);         // v % HW4
    return (size_t)b * 3 * HW + (size_t)hw4 * 4;
}

__device__ __forceinline__ void do_quad(const float* __restrict__ in,
                                        float* __restrict__ out,
                                        size_t base,
                                        f32x4 a0, f32x4 a1, f32x4 a2) {
    Px rx = px(a0.x, a1.x, a2.x);
    Px ry = px(a0.y, a1.y, a2.y);
    Px rz = px(a0.z, a1.z, a2.z);
    Px rw = px(a0.w, a1.w, a2.w);

    f32x4 o0 = { rx.o0, ry.o0, rz.o0, rw.o0 };
    f32x4 o1 = { rx.o1, ry.o1, rz.o1, rw.o1 };
    f32x4 o2 = { rx.o2, ry.o2, rz.o2, rw.o2 };

    __builtin_nontemporal_store(o0, reinterpret_cast<f32x4*>(out + base));
    __builtin_nontemporal_store(o1, reinterpret_cast<f32x4*>(out + base + HW));
    __builtin_nontemporal_store(o2, reinterpret_cast<f32x4*>(out + base + 2 * HW));
}

__global__ void __launch_bounds__(256)
transforms_blue_kernel(const float* __restrict__ in, float* __restrict__ out) {
    const int tid = blockIdx.x * 256 + threadIdx.x;

    const size_t baseA = quad_base(tid);
    const size_t baseB = quad_base(tid + NTHREADS);

    // Issue all 6 loads before any compute: 6 outstanding vmem ops/thread.
    f32x4 A0 = __builtin_nontemporal_load(reinterpret_cast<const f32x4*>(in + baseA));
    f32x4 A1 = __builtin_nontemporal_load(reinterpret_cast<const f32x4*>(in + baseA + HW));
    f32x4 A2 = __builtin_nontemporal_load(reinterpret_cast<const f32x4*>(in + baseA + 2 * HW));
    f32x4 B0 = __builtin_nontemporal_load(reinterpret_cast<const f32x4*>(in + baseB));
    f32x4 B1 = __builtin_nontemporal_load(reinterpret_cast<const f32x4*>(in + baseB + HW));
    f32x4 B2 = __builtin_nontemporal_load(reinterpret_cast<const f32x4*>(in + baseB + 2 * HW));

    do_quad(in, out, baseA, A0, A1, A2);
    do_quad(in, out, baseB, B0, B1, B2);
}

extern "C" void kernel_launch(void* const* d_in, const int* in_sizes, int n_in,
                              void* d_out, int out_size, void* d_ws, size_t ws_size,
                              hipStream_t stream) {
    const float* in = (const float*)d_in[0];
    float* out = (float*)d_out;

    // 8192 blocks x 256 threads x 2 quads = 4,194,304 quads = 64*3*512*512/4... 
    // (NB * HW4 = 4,194,304; exact cover, no tail)
    transforms_blue_kernel<<<8192, 256, 0, stream>>>(in, out);
}